// Round 2
// baseline (358.855 us; speedup 1.0000x reference)
//
#include <hip/hip_runtime.h>
#include <hip/hip_bf16.h>

#define B_  32
#define T_  2048
#define DH_ 1024
#define DS_ 1024
#define A_  512
#define M_  (B_ * T_)   // 65536

typedef __attribute__((ext_vector_type(8))) short bf16x8;
typedef __attribute__((ext_vector_type(4))) float f32x4;

__device__ __forceinline__ unsigned short f2bf(float f) {
    union { float f; unsigned u; } v; v.f = f;
    unsigned r = 0x7FFFu + ((v.u >> 16) & 1u);
    return (unsigned short)((v.u + r) >> 16);
}
__device__ __forceinline__ float bflo(unsigned u) {
    union { unsigned u; float f; } v; v.u = u << 16; return v.f;
}
__device__ __forceinline__ float bfhi(unsigned u) {
    union { unsigned u; float f; } v; v.u = u & 0xFFFF0000u; return v.f;
}
__device__ __forceinline__ float fast_tanh(float x) {
    float cx = fminf(fmaxf(x, -9.f), 9.f);
    float e2 = __expf(2.f * cx);
    return (e2 - 1.f) / (e2 + 1.f);
}

// ---- zero e [M_] and c [B_*DH_] ------------------------------------------
__global__ void zero_kernel(float* __restrict__ e, float* __restrict__ c) {
    int i = blockIdx.x * blockDim.x + threadIdx.x;
    if (i < M_) e[i] = 0.f;
    int j = i - M_;
    if (j >= 0 && j < B_ * DH_) c[j] = 0.f;
}

// ---- U_t[a][k] = bf16(U_a[k][a]) -----------------------------------------
__global__ void prep_ut(const float* __restrict__ U, unsigned short* __restrict__ Ut) {
    int o = blockIdx.x * 256 + threadIdx.x;
    int a = o >> 10, k = o & (DH_ - 1);
    Ut[o] = f2bf(U[k * A_ + a]);
}

// ---- hb = bf16(h), 8 elems/thread ----------------------------------------
__global__ void conv_h(const float* __restrict__ h, unsigned int* __restrict__ hb) {
    size_t i = ((size_t)blockIdx.x * 256 + threadIdx.x) * 8;
    float4 a = *(const float4*)(h + i);
    float4 b = *(const float4*)(h + i + 4);
    uint4 o;
    o.x = (unsigned)f2bf(a.x) | ((unsigned)f2bf(a.y) << 16);
    o.y = (unsigned)f2bf(a.z) | ((unsigned)f2bf(a.w) << 16);
    o.z = (unsigned)f2bf(b.x) | ((unsigned)f2bf(b.y) << 16);
    o.w = (unsigned)f2bf(b.z) | ((unsigned)f2bf(b.w) << 16);
    *(uint4*)(hb + i / 2) = o;
}

// ---- Ws[b][a] = s[b,:] . W_a[:,a] ----------------------------------------
__global__ void ws_gemv(const float* __restrict__ s, const float* __restrict__ W,
                        float* __restrict__ Ws) {
    int idx = blockIdx.x * 256 + threadIdx.x;
    int b = idx >> 9, a = idx & (A_ - 1);
    const float* sp = s + b * DS_;
    float acc = 0.f;
#pragma unroll 4
    for (int k = 0; k < DS_; ++k) acc += sp[k] * W[k * A_ + a];
    Ws[idx] = acc;
}

// ---- main MFMA GEMM (bf16 in, global_load_lds staging) + fused epilogue --
__global__ void gemm_e_bf(const unsigned short* __restrict__ hb,
                          const unsigned short* __restrict__ Ut,
                          const float* __restrict__ Ws, const float* __restrict__ va,
                          float* __restrict__ e) {
    __shared__ unsigned short As[2][128][32];   // linear: global_load_lds dest
    __shared__ unsigned short Bs[2][128][32];

    const int tid = threadIdx.x;
    const int bid = blockIdx.x;
    const int tn = bid & 3, tm = bid >> 2;      // n-tiles fast -> A-panel L2 reuse
    const int rowBase = tm * 128, nBase = tn * 128;
    const int lane = tid & 63;
    const int wid = tid >> 6;
    const int wm = wid >> 1, wn = wid & 1;
    const int lr = lane & 15, kg = lane >> 4;

    f32x4 acc[4][4];
#pragma unroll
    for (int i = 0; i < 4; ++i)
#pragma unroll
        for (int j = 0; j < 4; ++j) acc[i][j] = (f32x4){0.f, 0.f, 0.f, 0.f};

    // staging geometry: byteIdx = q*4096 + tid*16 within the 8 KB tile
    const int sRow0 = (tid * 16) >> 6;          // q=0 row (0..63)
    const int sCol  = ((tid * 16) & 63) >> 1;   // bf16 col (0,8,16,24)

    auto stage = [&](int buf, int k0) {
#pragma unroll
        for (int q = 0; q < 2; ++q) {
            int row = q * 64 + sRow0;
            int ldsOff = q * 2048 + tid * 8;    // in bf16 elements
            const unsigned short* ga = hb + (size_t)(rowBase + row) * DH_ + k0 + sCol;
            __builtin_amdgcn_global_load_lds(
                (const __attribute__((address_space(1))) unsigned int*)ga,
                (__attribute__((address_space(3))) unsigned int*)(&As[buf][0][0] + ldsOff),
                16, 0, 0);
            const unsigned short* gb = Ut + (size_t)(nBase + row) * DH_ + k0 + sCol;
            __builtin_amdgcn_global_load_lds(
                (const __attribute__((address_space(1))) unsigned int*)gb,
                (__attribute__((address_space(3))) unsigned int*)(&Bs[buf][0][0] + ldsOff),
                16, 0, 0);
        }
    };

    stage(0, 0);
    __syncthreads();

#pragma unroll 1
    for (int kt = 0; kt < DH_ / 32; ++kt) {
        int buf = kt & 1;
        if (kt < DH_ / 32 - 1) stage(buf ^ 1, (kt + 1) * 32);

        bf16x8 af[4], bfv[4];
#pragma unroll
        for (int mi = 0; mi < 4; ++mi)
            af[mi] = *(const bf16x8*)(&As[buf][wm * 64 + mi * 16 + lr][kg * 8]);
#pragma unroll
        for (int ni = 0; ni < 4; ++ni)
            bfv[ni] = *(const bf16x8*)(&Bs[buf][wn * 64 + ni * 16 + lr][kg * 8]);
#pragma unroll
        for (int mi = 0; mi < 4; ++mi)
#pragma unroll
            for (int ni = 0; ni < 4; ++ni)
                acc[mi][ni] = __builtin_amdgcn_mfma_f32_16x16x32_bf16(
                    af[mi], bfv[ni], acc[mi][ni], 0, 0, 0);
        __syncthreads();
    }

    // epilogue: e[row] += sum_a tanh(acc + Ws[b][a]) * v[a]
    const int bIdx = rowBase >> 11;
    const float* WsRow = Ws + bIdx * A_;
    float wsv[4], vav[4];
#pragma unroll
    for (int ni = 0; ni < 4; ++ni) {
        int a = nBase + wn * 64 + ni * 16 + lr;
        wsv[ni] = WsRow[a];
        vav[ni] = va[a];
    }
#pragma unroll
    for (int mi = 0; mi < 4; ++mi) {
#pragma unroll
        for (int j = 0; j < 4; ++j) {
            float ssum = 0.f;
#pragma unroll
            for (int ni = 0; ni < 4; ++ni) {
                float x = acc[mi][ni][j] + wsv[ni];
                ssum += fast_tanh(x) * vav[ni];
            }
            ssum += __shfl_xor(ssum, 1);
            ssum += __shfl_xor(ssum, 2);
            ssum += __shfl_xor(ssum, 4);
            ssum += __shfl_xor(ssum, 8);
            if (lr == 0) {
                int row = rowBase + wm * 64 + mi * 16 + (lane >> 4) * 4 + j;
                atomicAdd(&e[row], ssum);
            }
        }
    }
}

// ---- fallback GEMM (f32 h, reg-staged) — used only if ws too small -------
__global__ void gemm_e_f32(const float* __restrict__ h, const unsigned short* __restrict__ Ut,
                           const float* __restrict__ Ws, const float* __restrict__ va,
                           float* __restrict__ e) {
    __shared__ unsigned short As[2][128][40];
    __shared__ unsigned short Bs[2][128][40];
    const int tid = threadIdx.x;
    const int bid = blockIdx.x;
    const int tn = bid & 3, tm = bid >> 2;
    const int rowBase = tm * 128, nBase = tn * 128;
    const int wid = tid >> 6, lane = tid & 63;
    const int wm = wid >> 1, wn = wid & 1;
    const int lr = lane & 15, kg = lane >> 4;
    const int sr = tid >> 3;
    const int kq = (tid & 7) << 2;
    f32x4 acc[4][4];
#pragma unroll
    for (int i = 0; i < 4; ++i)
#pragma unroll
        for (int j = 0; j < 4; ++j) acc[i][j] = (f32x4){0.f, 0.f, 0.f, 0.f};
    auto stage = [&](int buf, int k0) {
#pragma unroll
        for (int p = 0; p < 4; ++p) {
            int row = p * 32 + sr;
            const float4 hv = *(const float4*)(h + (size_t)(rowBase + row) * DH_ + k0 + kq);
            ushort4 u;
            u.x = f2bf(hv.x); u.y = f2bf(hv.y); u.z = f2bf(hv.z); u.w = f2bf(hv.w);
            *(ushort4*)(&As[buf][row][kq]) = u;
            ushort4 bv = *(const ushort4*)(Ut + (size_t)(nBase + row) * DH_ + k0 + kq);
            *(ushort4*)(&Bs[buf][row][kq]) = bv;
        }
    };
    stage(0, 0);
    __syncthreads();
#pragma unroll 1
    for (int kt = 0; kt < DH_ / 32; ++kt) {
        int buf = kt & 1;
        if (kt < DH_ / 32 - 1) stage(buf ^ 1, (kt + 1) * 32);
        bf16x8 af[4], bfv[4];
#pragma unroll
        for (int mi = 0; mi < 4; ++mi)
            af[mi] = *(const bf16x8*)(&As[buf][wm * 64 + mi * 16 + lr][kg * 8]);
#pragma unroll
        for (int ni = 0; ni < 4; ++ni)
            bfv[ni] = *(const bf16x8*)(&Bs[buf][wn * 64 + ni * 16 + lr][kg * 8]);
#pragma unroll
        for (int mi = 0; mi < 4; ++mi)
#pragma unroll
            for (int ni = 0; ni < 4; ++ni)
                acc[mi][ni] = __builtin_amdgcn_mfma_f32_16x16x32_bf16(
                    af[mi], bfv[ni], acc[mi][ni], 0, 0, 0);
        __syncthreads();
    }
    const int bIdx = rowBase >> 11;
    const float* WsRow = Ws + bIdx * A_;
    float wsv[4], vav[4];
#pragma unroll
    for (int ni = 0; ni < 4; ++ni) {
        int a = nBase + wn * 64 + ni * 16 + lr;
        wsv[ni] = WsRow[a];
        vav[ni] = va[a];
    }
#pragma unroll
    for (int mi = 0; mi < 4; ++mi) {
#pragma unroll
        for (int j = 0; j < 4; ++j) {
            float ssum = 0.f;
#pragma unroll
            for (int ni = 0; ni < 4; ++ni) {
                float x = acc[mi][ni][j] + wsv[ni];
                ssum += fast_tanh(x) * vav[ni];
            }
            ssum += __shfl_xor(ssum, 1);
            ssum += __shfl_xor(ssum, 2);
            ssum += __shfl_xor(ssum, 4);
            ssum += __shfl_xor(ssum, 8);
            if (lr == 0) {
                int row = rowBase + wm * 64 + mi * 16 + (lane >> 4) * 4 + j;
                atomicAdd(&e[row], ssum);
            }
        }
    }
}

// ---- softmax over T per batch (in place on e) ----------------------------
__global__ void softmax_kernel(float* __restrict__ e) {
    __shared__ float red[8];
    const int b = blockIdx.x, tid = threadIdx.x;
    float* ep = e + b * T_;
    float4 v0 = ((float4*)ep)[tid * 2];
    float4 v1 = ((float4*)ep)[tid * 2 + 1];
    float m = fmaxf(fmaxf(fmaxf(v0.x, v0.y), fmaxf(v0.z, v0.w)),
                    fmaxf(fmaxf(v1.x, v1.y), fmaxf(v1.z, v1.w)));
#pragma unroll
    for (int off = 1; off < 64; off <<= 1) m = fmaxf(m, __shfl_xor(m, off));
    int wid = tid >> 6;
    if ((tid & 63) == 0) red[wid] = m;
    __syncthreads();
    m = fmaxf(fmaxf(red[0], red[1]), fmaxf(red[2], red[3]));
    v0.x = __expf(v0.x - m); v0.y = __expf(v0.y - m);
    v0.z = __expf(v0.z - m); v0.w = __expf(v0.w - m);
    v1.x = __expf(v1.x - m); v1.y = __expf(v1.y - m);
    v1.z = __expf(v1.z - m); v1.w = __expf(v1.w - m);
    float ssum = v0.x + v0.y + v0.z + v0.w + v1.x + v1.y + v1.z + v1.w;
#pragma unroll
    for (int off = 1; off < 64; off <<= 1) ssum += __shfl_xor(ssum, off);
    if ((tid & 63) == 0) red[4 + wid] = ssum;
    __syncthreads();
    float inv = 1.f / (red[4] + red[5] + red[6] + red[7]);
    v0.x *= inv; v0.y *= inv; v0.z *= inv; v0.w *= inv;
    v1.x *= inv; v1.y *= inv; v1.z *= inv; v1.w *= inv;
    ((float4*)ep)[tid * 2] = v0;
    ((float4*)ep)[tid * 2 + 1] = v1;
}

// ---- c[b][d] = sum_t a[b][t] * hb[b][t][d]  (bf16 h) ----------------------
__global__ void ctx_bf(const unsigned int* __restrict__ hb, const float* __restrict__ a,
                       float* __restrict__ c) {
    const int bid = blockIdx.x;
    const int b = bid >> 5, seg = bid & 31;
    const int tid = threadIdx.x;
    const int half = tid >> 7;                 // 0/1 interleaved t
    const int d0 = (tid & 127) * 8;
    const int t0 = seg * 64 + half;
    float acc[8] = {0.f, 0.f, 0.f, 0.f, 0.f, 0.f, 0.f, 0.f};
    const unsigned int* hp = hb + (((size_t)b * T_ + t0) * DH_ + d0) / 2;
    const float* ap = a + (size_t)b * T_ + t0;
#pragma unroll 4
    for (int t = 0; t < 64; t += 2) {
        float w = ap[t];
        uint4 v = *(const uint4*)(hp + (size_t)t * (DH_ / 2));
        acc[0] += w * bflo(v.x); acc[1] += w * bfhi(v.x);
        acc[2] += w * bflo(v.y); acc[3] += w * bfhi(v.y);
        acc[4] += w * bflo(v.z); acc[5] += w * bfhi(v.z);
        acc[6] += w * bflo(v.w); acc[7] += w * bfhi(v.w);
    }
    float* cp = c + (size_t)b * DH_ + d0;
#pragma unroll
    for (int j = 0; j < 8; ++j) atomicAdd(cp + j, acc[j]);
}

// ---- fallback ctx (f32 h) --------------------------------------------------
__global__ void ctx_f32(const float* __restrict__ h, const float* __restrict__ a,
                        float* __restrict__ c) {
    const int bid = blockIdx.x;
    const int b = bid >> 5, seg = bid & 31;
    const int tid = threadIdx.x;
    const int t0 = seg * 64;
    float4 acc = {0.f, 0.f, 0.f, 0.f};
    const float* hp = h + ((size_t)b * T_ + t0) * DH_ + tid * 4;
    const float* ap = a + b * T_ + t0;
#pragma unroll 4
    for (int t = 0; t < 64; ++t) {
        float w = ap[t];
        float4 hv = *(const float4*)(hp + (size_t)t * DH_);
        acc.x += w * hv.x; acc.y += w * hv.y;
        acc.z += w * hv.z; acc.w += w * hv.w;
    }
    float* cp = c + b * DH_ + tid * 4;
    atomicAdd(cp + 0, acc.x);
    atomicAdd(cp + 1, acc.y);
    atomicAdd(cp + 2, acc.z);
    atomicAdd(cp + 3, acc.w);
}

extern "C" void kernel_launch(void* const* d_in, const int* in_sizes, int n_in,
                              void* d_out, int out_size, void* d_ws, size_t ws_size,
                              hipStream_t stream) {
    const float* s   = (const float*)d_in[0];
    const float* h   = (const float*)d_in[1];
    const float* W_a = (const float*)d_in[2];
    const float* U_a = (const float*)d_in[3];
    const float* v_a = (const float*)d_in[4];
    float* c = (float*)d_out;

    // workspace layout (bytes): e | Ws | Ut | hb
    const size_t off_Ws = (size_t)M_ * 4;                 // 262144
    const size_t off_Ut = off_Ws + (size_t)B_ * A_ * 4;   // +65536
    const size_t off_hb = off_Ut + (size_t)A_ * DH_ * 2;  // +1048576
    const size_t need   = off_hb + (size_t)M_ * DH_ * 2;  // +128 MiB

    float* e  = (float*)d_ws;
    float* Ws = (float*)((char*)d_ws + off_Ws);
    unsigned short* Ut = (unsigned short*)((char*)d_ws + off_Ut);

    zero_kernel<<<(M_ + B_ * DH_ + 255) / 256, 256, 0, stream>>>(e, c);
    prep_ut<<<(A_ * DH_) / 256, 256, 0, stream>>>(U_a, Ut);
    ws_gemv<<<(B_ * A_) / 256, 256, 0, stream>>>(s, W_a, Ws);

    if (ws_size >= need) {
        unsigned int* hb = (unsigned int*)((char*)d_ws + off_hb);
        conv_h<<<(M_ * (size_t)DH_) / (256 * 8), 256, 0, stream>>>(h, hb);
        gemm_e_bf<<<(M_ / 128) * (A_ / 128), 256, 0, stream>>>(
            (const unsigned short*)hb, Ut, Ws, v_a, e);
        softmax_kernel<<<B_, 256, 0, stream>>>(e);
        ctx_bf<<<B_ * 32, 256, 0, stream>>>(hb, e, c);
    } else {
        gemm_e_f32<<<(M_ / 128) * (A_ / 128), 256, 0, stream>>>(h, Ut, Ws, v_a, e);
        softmax_kernel<<<B_, 256, 0, stream>>>(e);
        ctx_f32<<<B_ * 32, 256, 0, stream>>>(h, e, c);
    }
}

// Round 3
// 354.027 us; speedup vs baseline: 1.0136x; 1.0136x over previous
//
#include <hip/hip_runtime.h>
#include <hip/hip_bf16.h>

#define B_  32
#define T_  2048
#define DH_ 1024
#define DS_ 1024
#define A_  512
#define M_  (B_ * T_)   // 65536

typedef __attribute__((ext_vector_type(8))) short bf16x8;
typedef __attribute__((ext_vector_type(4))) float f32x4;

__device__ __forceinline__ unsigned short f2bf(float f) {
    union { float f; unsigned u; } v; v.f = f;
    unsigned r = 0x7FFFu + ((v.u >> 16) & 1u);
    return (unsigned short)((v.u + r) >> 16);
}
__device__ __forceinline__ float bflo(unsigned u) {
    union { unsigned u; float f; } v; v.u = u << 16; return v.f;
}
__device__ __forceinline__ float bfhi(unsigned u) {
    union { unsigned u; float f; } v; v.u = u & 0xFFFF0000u; return v.f;
}
__device__ __forceinline__ float fast_tanh(float x) {
    float cx = fminf(fmaxf(x, -9.f), 9.f);
    float e2 = __expf(2.f * cx);
    return (e2 - 1.f) / (e2 + 1.f);
}

// ---- zero e [M_] and c [B_*DH_] ------------------------------------------
__global__ void zero_kernel(float* __restrict__ e, float* __restrict__ c) {
    int i = blockIdx.x * blockDim.x + threadIdx.x;
    if (i < M_) e[i] = 0.f;
    int j = i - M_;
    if (j >= 0 && j < B_ * DH_) c[j] = 0.f;
}

// ---- U_t[a][k] = bf16(U_a[k][a]) -----------------------------------------
__global__ void prep_ut(const float* __restrict__ U, unsigned short* __restrict__ Ut) {
    int o = blockIdx.x * 256 + threadIdx.x;
    int a = o >> 10, k = o & (DH_ - 1);
    Ut[o] = f2bf(U[k * A_ + a]);
}

// ---- hb = bf16(h), 8 elems/thread ----------------------------------------
__global__ void conv_h(const float* __restrict__ h, unsigned int* __restrict__ hb) {
    size_t i = ((size_t)blockIdx.x * 256 + threadIdx.x) * 8;
    float4 a = *(const float4*)(h + i);
    float4 b = *(const float4*)(h + i + 4);
    uint4 o;
    o.x = (unsigned)f2bf(a.x) | ((unsigned)f2bf(a.y) << 16);
    o.y = (unsigned)f2bf(a.z) | ((unsigned)f2bf(a.w) << 16);
    o.z = (unsigned)f2bf(b.x) | ((unsigned)f2bf(b.y) << 16);
    o.w = (unsigned)f2bf(b.z) | ((unsigned)f2bf(b.w) << 16);
    *(uint4*)(hb + i / 2) = o;
}

// ---- Ws[b][a] = s[b,:] . W_a[:,a] ----------------------------------------
__global__ void ws_gemv(const float* __restrict__ s, const float* __restrict__ W,
                        float* __restrict__ Ws) {
    int idx = blockIdx.x * 256 + threadIdx.x;
    int b = idx >> 9, a = idx & (A_ - 1);
    const float* sp = s + b * DS_;
    float acc = 0.f;
#pragma unroll 4
    for (int k = 0; k < DS_; ++k) acc += sp[k] * W[k * A_ + a];
    Ws[idx] = acc;
}

// ---- main MFMA GEMM (bf16 in, global_load_lds staging) + fused epilogue --
// XCD-chunked swizzle: the 4 tn-sharers of each A-panel run on the SAME XCD.
__global__ void gemm_e_bf(const unsigned short* __restrict__ hb,
                          const unsigned short* __restrict__ Ut,
                          const float* __restrict__ Ws, const float* __restrict__ va,
                          float* __restrict__ e) {
    __shared__ unsigned short As[2][128][32];   // linear: global_load_lds dest
    __shared__ unsigned short Bs[2][128][32];

    const int tid = threadIdx.x;
    // bijective XCD-chunk swizzle (nwg = 2048, 8 XCDs, 256 wg/XCD)
    const int bid0 = blockIdx.x;
    const int bid = (bid0 & 7) * 256 + (bid0 >> 3);
    const int tn = bid & 3, tm = bid >> 2;      // tn fast: A-panel shared within XCD
    const int rowBase = tm * 128, nBase = tn * 128;
    const int lane = tid & 63;
    const int wid = tid >> 6;
    const int wm = wid >> 1, wn = wid & 1;
    const int lr = lane & 15, kg = lane >> 4;

    f32x4 acc[4][4];
#pragma unroll
    for (int i = 0; i < 4; ++i)
#pragma unroll
        for (int j = 0; j < 4; ++j) acc[i][j] = (f32x4){0.f, 0.f, 0.f, 0.f};

    // staging geometry: byteIdx = q*4096 + tid*16 within the 8 KB tile
    const int sRow0 = (tid * 16) >> 6;          // q=0 row (0..63)
    const int sCol  = ((tid * 16) & 63) >> 1;   // bf16 col (0,8,16,24)

    auto stage = [&](int buf, int k0) {
#pragma unroll
        for (int q = 0; q < 2; ++q) {
            int row = q * 64 + sRow0;
            int ldsOff = q * 2048 + tid * 8;    // in bf16 elements
            const unsigned short* ga = hb + (size_t)(rowBase + row) * DH_ + k0 + sCol;
            __builtin_amdgcn_global_load_lds(
                (const __attribute__((address_space(1))) unsigned int*)ga,
                (__attribute__((address_space(3))) unsigned int*)(&As[buf][0][0] + ldsOff),
                16, 0, 0);
            const unsigned short* gb = Ut + (size_t)(nBase + row) * DH_ + k0 + sCol;
            __builtin_amdgcn_global_load_lds(
                (const __attribute__((address_space(1))) unsigned int*)gb,
                (__attribute__((address_space(3))) unsigned int*)(&Bs[buf][0][0] + ldsOff),
                16, 0, 0);
        }
    };

    stage(0, 0);
    __syncthreads();

#pragma unroll 1
    for (int kt = 0; kt < DH_ / 32; ++kt) {
        int buf = kt & 1;
        if (kt < DH_ / 32 - 1) stage(buf ^ 1, (kt + 1) * 32);

        bf16x8 af[4], bfv[4];
#pragma unroll
        for (int mi = 0; mi < 4; ++mi)
            af[mi] = *(const bf16x8*)(&As[buf][wm * 64 + mi * 16 + lr][kg * 8]);
#pragma unroll
        for (int ni = 0; ni < 4; ++ni)
            bfv[ni] = *(const bf16x8*)(&Bs[buf][wn * 64 + ni * 16 + lr][kg * 8]);
#pragma unroll
        for (int mi = 0; mi < 4; ++mi)
#pragma unroll
            for (int ni = 0; ni < 4; ++ni)
                acc[mi][ni] = __builtin_amdgcn_mfma_f32_16x16x32_bf16(
                    af[mi], bfv[ni], acc[mi][ni], 0, 0, 0);
        __syncthreads();
    }

    // epilogue: e[row] += sum_a tanh(acc + Ws[b][a]) * v[a]
    const int bIdx = rowBase >> 11;
    const float* WsRow = Ws + bIdx * A_;
    float wsv[4], vav[4];
#pragma unroll
    for (int ni = 0; ni < 4; ++ni) {
        int a = nBase + wn * 64 + ni * 16 + lr;
        wsv[ni] = WsRow[a];
        vav[ni] = va[a];
    }
#pragma unroll
    for (int mi = 0; mi < 4; ++mi) {
#pragma unroll
        for (int j = 0; j < 4; ++j) {
            float ssum = 0.f;
#pragma unroll
            for (int ni = 0; ni < 4; ++ni) {
                float x = acc[mi][ni][j] + wsv[ni];
                ssum += fast_tanh(x) * vav[ni];
            }
            ssum += __shfl_xor(ssum, 1);
            ssum += __shfl_xor(ssum, 2);
            ssum += __shfl_xor(ssum, 4);
            ssum += __shfl_xor(ssum, 8);
            if (lr == 0) {
                int row = rowBase + wm * 64 + mi * 16 + (lane >> 4) * 4 + j;
                atomicAdd(&e[row], ssum);
            }
        }
    }
}

// ---- fallback GEMM (f32 h, reg-staged) — used only if ws too small -------
__global__ void gemm_e_f32(const float* __restrict__ h, const unsigned short* __restrict__ Ut,
                           const float* __restrict__ Ws, const float* __restrict__ va,
                           float* __restrict__ e) {
    __shared__ unsigned short As[2][128][40];
    __shared__ unsigned short Bs[2][128][40];
    const int tid = threadIdx.x;
    const int bid = blockIdx.x;
    const int tn = bid & 3, tm = bid >> 2;
    const int rowBase = tm * 128, nBase = tn * 128;
    const int wid = tid >> 6, lane = tid & 63;
    const int wm = wid >> 1, wn = wid & 1;
    const int lr = lane & 15, kg = lane >> 4;
    const int sr = tid >> 3;
    const int kq = (tid & 7) << 2;
    f32x4 acc[4][4];
#pragma unroll
    for (int i = 0; i < 4; ++i)
#pragma unroll
        for (int j = 0; j < 4; ++j) acc[i][j] = (f32x4){0.f, 0.f, 0.f, 0.f};
    auto stage = [&](int buf, int k0) {
#pragma unroll
        for (int p = 0; p < 4; ++p) {
            int row = p * 32 + sr;
            const float4 hv = *(const float4*)(h + (size_t)(rowBase + row) * DH_ + k0 + kq);
            ushort4 u;
            u.x = f2bf(hv.x); u.y = f2bf(hv.y); u.z = f2bf(hv.z); u.w = f2bf(hv.w);
            *(ushort4*)(&As[buf][row][kq]) = u;
            ushort4 bv = *(const ushort4*)(Ut + (size_t)(nBase + row) * DH_ + k0 + kq);
            *(ushort4*)(&Bs[buf][row][kq]) = bv;
        }
    };
    stage(0, 0);
    __syncthreads();
#pragma unroll 1
    for (int kt = 0; kt < DH_ / 32; ++kt) {
        int buf = kt & 1;
        if (kt < DH_ / 32 - 1) stage(buf ^ 1, (kt + 1) * 32);
        bf16x8 af[4], bfv[4];
#pragma unroll
        for (int mi = 0; mi < 4; ++mi)
            af[mi] = *(const bf16x8*)(&As[buf][wm * 64 + mi * 16 + lr][kg * 8]);
#pragma unroll
        for (int ni = 0; ni < 4; ++ni)
            bfv[ni] = *(const bf16x8*)(&Bs[buf][wn * 64 + ni * 16 + lr][kg * 8]);
#pragma unroll
        for (int mi = 0; mi < 4; ++mi)
#pragma unroll
            for (int ni = 0; ni < 4; ++ni)
                acc[mi][ni] = __builtin_amdgcn_mfma_f32_16x16x32_bf16(
                    af[mi], bfv[ni], acc[mi][ni], 0, 0, 0);
        __syncthreads();
    }
    const int bIdx = rowBase >> 11;
    const float* WsRow = Ws + bIdx * A_;
    float wsv[4], vav[4];
#pragma unroll
    for (int ni = 0; ni < 4; ++ni) {
        int a = nBase + wn * 64 + ni * 16 + lr;
        wsv[ni] = WsRow[a];
        vav[ni] = va[a];
    }
#pragma unroll
    for (int mi = 0; mi < 4; ++mi) {
#pragma unroll
        for (int j = 0; j < 4; ++j) {
            float ssum = 0.f;
#pragma unroll
            for (int ni = 0; ni < 4; ++ni) {
                float x = acc[mi][ni][j] + wsv[ni];
                ssum += fast_tanh(x) * vav[ni];
            }
            ssum += __shfl_xor(ssum, 1);
            ssum += __shfl_xor(ssum, 2);
            ssum += __shfl_xor(ssum, 4);
            ssum += __shfl_xor(ssum, 8);
            if (lr == 0) {
                int row = rowBase + wm * 64 + mi * 16 + (lane >> 4) * 4 + j;
                atomicAdd(&e[row], ssum);
            }
        }
    }
}

// ---- softmax over T per batch (in place on e) ----------------------------
__global__ void softmax_kernel(float* __restrict__ e) {
    __shared__ float red[8];
    const int b = blockIdx.x, tid = threadIdx.x;
    float* ep = e + b * T_;
    float4 v0 = ((float4*)ep)[tid * 2];
    float4 v1 = ((float4*)ep)[tid * 2 + 1];
    float m = fmaxf(fmaxf(fmaxf(v0.x, v0.y), fmaxf(v0.z, v0.w)),
                    fmaxf(fmaxf(v1.x, v1.y), fmaxf(v1.z, v1.w)));
#pragma unroll
    for (int off = 1; off < 64; off <<= 1) m = fmaxf(m, __shfl_xor(m, off));
    int wid = tid >> 6;
    if ((tid & 63) == 0) red[wid] = m;
    __syncthreads();
    m = fmaxf(fmaxf(red[0], red[1]), fmaxf(red[2], red[3]));
    v0.x = __expf(v0.x - m); v0.y = __expf(v0.y - m);
    v0.z = __expf(v0.z - m); v0.w = __expf(v0.w - m);
    v1.x = __expf(v1.x - m); v1.y = __expf(v1.y - m);
    v1.z = __expf(v1.z - m); v1.w = __expf(v1.w - m);
    float ssum = v0.x + v0.y + v0.z + v0.w + v1.x + v1.y + v1.z + v1.w;
#pragma unroll
    for (int off = 1; off < 64; off <<= 1) ssum += __shfl_xor(ssum, off);
    if ((tid & 63) == 0) red[4 + wid] = ssum;
    __syncthreads();
    float inv = 1.f / (red[4] + red[5] + red[6] + red[7]);
    v0.x *= inv; v0.y *= inv; v0.z *= inv; v0.w *= inv;
    v1.x *= inv; v1.y *= inv; v1.z *= inv; v1.w *= inv;
    ((float4*)ep)[tid * 2] = v0;
    ((float4*)ep)[tid * 2 + 1] = v1;
}

// ---- c[b][d] = sum_t a[b][t] * hb[b][t][d]  (bf16 h) ----------------------
__global__ void ctx_bf(const unsigned int* __restrict__ hb, const float* __restrict__ a,
                       float* __restrict__ c) {
    const int bid = blockIdx.x;
    const int b = bid >> 5, seg = bid & 31;
    const int tid = threadIdx.x;
    const int half = tid >> 7;                 // 0/1 interleaved t
    const int d0 = (tid & 127) * 8;
    const int t0 = seg * 64 + half;
    float acc[8] = {0.f, 0.f, 0.f, 0.f, 0.f, 0.f, 0.f, 0.f};
    const unsigned int* hp = hb + (((size_t)b * T_ + t0) * DH_ + d0) / 2;
    const float* ap = a + (size_t)b * T_ + t0;
#pragma unroll 4
    for (int t = 0; t < 64; t += 2) {
        float w = ap[t];
        uint4 v = *(const uint4*)(hp + (size_t)t * (DH_ / 2));
        acc[0] += w * bflo(v.x); acc[1] += w * bfhi(v.x);
        acc[2] += w * bflo(v.y); acc[3] += w * bfhi(v.y);
        acc[4] += w * bflo(v.z); acc[5] += w * bfhi(v.z);
        acc[6] += w * bflo(v.w); acc[7] += w * bfhi(v.w);
    }
    float* cp = c + (size_t)b * DH_ + d0;
#pragma unroll
    for (int j = 0; j < 8; ++j) atomicAdd(cp + j, acc[j]);
}

// ---- fallback ctx (f32 h) --------------------------------------------------
__global__ void ctx_f32(const float* __restrict__ h, const float* __restrict__ a,
                        float* __restrict__ c) {
    const int bid = blockIdx.x;
    const int b = bid >> 5, seg = bid & 31;
    const int tid = threadIdx.x;
    const int t0 = seg * 64;
    float4 acc = {0.f, 0.f, 0.f, 0.f};
    const float* hp = h + ((size_t)b * T_ + t0) * DH_ + tid * 4;
    const float* ap = a + b * T_ + t0;
#pragma unroll 4
    for (int t = 0; t < 64; ++t) {
        float w = ap[t];
        float4 hv = *(const float4*)(hp + (size_t)t * DH_);
        acc.x += w * hv.x; acc.y += w * hv.y;
        acc.z += w * hv.z; acc.w += w * hv.w;
    }
    float* cp = c + b * DH_ + tid * 4;
    atomicAdd(cp + 0, acc.x);
    atomicAdd(cp + 1, acc.y);
    atomicAdd(cp + 2, acc.z);
    atomicAdd(cp + 3, acc.w);
}

extern "C" void kernel_launch(void* const* d_in, const int* in_sizes, int n_in,
                              void* d_out, int out_size, void* d_ws, size_t ws_size,
                              hipStream_t stream) {
    const float* s   = (const float*)d_in[0];
    const float* h   = (const float*)d_in[1];
    const float* W_a = (const float*)d_in[2];
    const float* U_a = (const float*)d_in[3];
    const float* v_a = (const float*)d_in[4];
    float* c = (float*)d_out;

    // workspace layout (bytes): e | Ws | Ut | hb
    const size_t off_Ws = (size_t)M_ * 4;                 // 262144
    const size_t off_Ut = off_Ws + (size_t)B_ * A_ * 4;   // +65536
    const size_t off_hb = off_Ut + (size_t)A_ * DH_ * 2;  // +1048576
    const size_t need   = off_hb + (size_t)M_ * DH_ * 2;  // +128 MiB

    float* e  = (float*)d_ws;
    float* Ws = (float*)((char*)d_ws + off_Ws);
    unsigned short* Ut = (unsigned short*)((char*)d_ws + off_Ut);

    zero_kernel<<<(M_ + B_ * DH_ + 255) / 256, 256, 0, stream>>>(e, c);
    prep_ut<<<(A_ * DH_) / 256, 256, 0, stream>>>(U_a, Ut);
    ws_gemv<<<(B_ * A_) / 256, 256, 0, stream>>>(s, W_a, Ws);

    if (ws_size >= need) {
        unsigned int* hb = (unsigned int*)((char*)d_ws + off_hb);
        conv_h<<<(M_ * (size_t)DH_) / (256 * 8), 256, 0, stream>>>(h, hb);
        gemm_e_bf<<<(M_ / 128) * (A_ / 128), 256, 0, stream>>>(
            (const unsigned short*)hb, Ut, Ws, v_a, e);
        softmax_kernel<<<B_, 256, 0, stream>>>(e);
        ctx_bf<<<B_ * 32, 256, 0, stream>>>(hb, e, c);
    } else {
        gemm_e_f32<<<(M_ / 128) * (A_ / 128), 256, 0, stream>>>(h, Ut, Ws, v_a, e);
        softmax_kernel<<<B_, 256, 0, stream>>>(e);
        ctx_f32<<<B_ * 32, 256, 0, stream>>>(h, e, c);
    }
}